// Round 9
// baseline (258.340 us; speedup 1.0000x reference)
//
#include <hip/hip_runtime.h>

// x: [8, 1, 160, 160, 160] fp32; log_sigma: [3] fp32; out: scalar fp32.
// loss = -(sum over 3816 (axis,b,pair) of exp(-sq/(2*sigma_axis^2))) / 3816.
//
// R9 = R6 skeleton with halo/flush cuts: thread owns 10 CONSECUTIVE rows x
// 1 float4-col x 5 slices (512 blocks = 8b x 32ds x 2 half-heights).
// d-halo 1/10 (was 1/5 per-row... 4-row R6: 1/5), h-halo 1/10 (was 1/4),
// flush per unique byte /2.5. h-halo row address CLAMPED (row 159 -> own row
// => zero diff) so no hOK branch. w-boundary via __shfl_down + lane-63 patch
// loads (R6-proven). Private slots, no atomics (R7 regressed), 3-kernel chain.

constexpr int Wd4 = 40;              // float4 per row
constexpr int SLICE4 = 6400;         // float4 per slice
constexpr long BSTR4 = 160L * 6400;  // float4 per batch
constexpr int NB = 8;
constexpr int NPAIR = 159;
constexpr int NKEY = 3 * NB * NPAIR;   // 3816
constexpr int SLOT = 256;              // floats/slot: [0..4]=D [5..84]=H [85..244]=W
constexpr int NBLK = NB * 32 * 2;      // 512
constexpr int PART_OFF = NBLK * SLOT;  // float offset of reduce partials in ws
constexpr int NFIN = 60;

__device__ __forceinline__ float sq4(const float4& a, const float4& c) {
    float e0 = a.x - c.x, e1 = a.y - c.y, e2 = a.z - c.z, e3 = a.w - c.w;
    return e0 * e0 + e1 * e1 + e2 * e2 + e3 * e3;
}

// 512 blocks x 320 threads. bid -> (b, ds 0..31, hg 0..1). Thread: c4=t%40,
// rp=t/40 owns rows 80hg+10rp+{0..9}, slices 5ds..5ds+4 (+halo slice, v only).
__global__ __launch_bounds__(320) void diff3_kernel(const float* __restrict__ x,
                                                    float* __restrict__ ws) {
    __shared__ float lds[3320];  // H: 80 keys*41 [0..3279]; D: [3280..3319]; W reuses [0..1439]

    const int t = threadIdx.x;
    const int bid = blockIdx.x;
    const int b = bid / 64;
    const int r2 = bid % 64;
    const int ds = r2 >> 1;          // 0..31, d0 = 5*ds
    const int hg = r2 & 1;           // 0..1,  h0 = 80*hg
    const int d0 = ds * 5, h0 = hg * 80;
    const bool lastSeg = (ds == 31);

    const int c4 = t % 40;
    const int rp = t / 40;                  // 0..7
    const int lane = t & 63;
    const int wv = t >> 6;                  // wave 0..4
    const bool sOK = (c4 < 39);
    const bool fixB = (lane == 63) && sOK;  // shfl partner in next wave -> patch loads
    // h-halo row = base+10 rows; clamp to row 159 (own row 9) => zero diff, no branch
    const int hvOff = (hg == 1 && rp == 7) ? 9 * Wd4 : 10 * Wd4;

    const float4* base = (const float4*)x + (size_t)b * BSTR4 + (size_t)d0 * SLICE4
                       + (size_t)(h0 + 10 * rp) * Wd4 + c4;

    float aW[4] = {0.f, 0.f, 0.f, 0.f};
    float aH[10], aD[5] = {0.f, 0.f, 0.f, 0.f, 0.f};
#pragma unroll
    for (int j = 0; j < 10; ++j) aH[j] = 0.f;
    float4 p[10];

#pragma unroll
    for (int it = 0; it < 5; ++it) {
        const float4* sp = base + it * SLICE4;
        float4 v[10];
#pragma unroll
        for (int j = 0; j < 10; ++j) v[j] = sp[j * Wd4];
        const float4 hv = sp[hvOff];
        float bx[10];
        if (fixB) {  // cross-wave w-boundary partners (4 threads/block)
            const float* fb = (const float*)sp;
#pragma unroll
            for (int j = 0; j < 10; ++j) bx[j] = fb[j * 160 + 4];
        }

#pragma unroll
        for (int j = 0; j < 10; ++j) {
            const float4 vj = v[j];
            float s = __shfl_down(vj.x, 1, 64);
            if (fixB) s = bx[j];
            float dw;
            dw = vj.y - vj.x; aW[0] += dw * dw;
            dw = vj.z - vj.y; aW[1] += dw * dw;
            dw = vj.w - vj.z; aW[2] += dw * dw;
            if (sOK) { dw = s - vj.w; aW[3] += dw * dw; }
        }
        // h: 9 register-local pairs + 1 via (clamped) hv
#pragma unroll
        for (int j = 0; j < 9; ++j) aH[j] += sq4(v[j + 1], v[j]);
        aH[9] += sq4(hv, v[9]);
        // d: pair d0+it-1 vs previous slice
        if (it > 0) {
            float dd = 0.f;
#pragma unroll
            for (int j = 0; j < 10; ++j) dd += sq4(v[j], p[j]);
            aD[it - 1] += dd;
        }
#pragma unroll
        for (int j = 0; j < 10; ++j) p[j] = v[j];  // SSA under full unroll
    }
    if (!lastSeg) {  // halo slice d0+5 (v only), completes pair key d0+4
        const float4* sp = base + 5 * SLICE4;
        float dd = 0.f;
#pragma unroll
        for (int j = 0; j < 10; ++j) dd += sq4(sp[j * Wd4], p[j]);
        aD[4] = dd;
    }

    // ---- flush. Phase 1: H per-key scratch + D wave-reduce.
#pragma unroll
    for (int j = 0; j < 10; ++j) lds[(10 * rp + j) * 41 + c4] = aH[j];
#pragma unroll
    for (int j = 0; j < 5; ++j) {
        float dd = aD[j];
        for (int off = 32; off > 0; off >>= 1) dd += __shfl_down(dd, off, 64);
        if (lane == 0) lds[3280 + j * 8 + wv] = dd;
    }
    __syncthreads();
    float hsum = 0.f, dsum = 0.f;
    if (t < 80) {
        const float* src = &lds[t * 41];
        for (int i = 0; i < 40; ++i) hsum += src[i];
    }
    if (t < 5) {
        for (int w2 = 0; w2 < 5; ++w2) dsum += lds[3280 + t * 8 + w2];
    }
    __syncthreads();  // H region reads done; reuse [0..1439] for W
    // Phase 2: W per-key scratch (key 4c4+j, 8 contributors rp).
#pragma unroll
    for (int j = 0; j < 4; ++j) lds[(4 * c4 + j) * 9 + rp] = aW[j];
    __syncthreads();
    float wsum = 0.f;
    if (t < 160) {
        const float* src = &lds[t * 9];
        for (int i = 0; i < 8; ++i) wsum += src[i];
    }
    // Private slot write (no atomics; unread slots harmless).
    float* slot = ws + (size_t)bid * SLOT;
    if (t < 5)   slot[t] = dsum;
    if (t < 80)  slot[5 + t] = hsum;
    if (t < 160) slot[85 + t] = wsum;
}

// 60 blocks x 64 threads: one thread per (axis,b,pair); sums contributing slots.
__global__ __launch_bounds__(64) void reduce_kernel(const float* __restrict__ ws,
                                                    const float* __restrict__ log_sigma,
                                                    float* __restrict__ part) {
    const int gk = blockIdx.x * 64 + threadIdx.x;
    float kv = 0.f;
    if (gk < NKEY) {
        const int a = gk / (NB * NPAIR);
        const int rem = gk % (NB * NPAIR);
        const int b = rem / NPAIR;
        const int k = rem % NPAIR;
        const float f = -0.5f * expf(-2.f * log_sigma[a]);  // -1/(2*sigma^2)
        const float* bb = ws + (size_t)b * 64 * SLOT;       // 64 slots per batch
        float val = 0.f;
        if (a == 0) {        // D: key k -> ds=k/5, j=k%5; sum over hg
            const int ds = k / 5, j = k % 5;
            const float* p = bb + (size_t)(ds * 2) * SLOT + j;
            val = p[0] + p[SLOT];
        } else if (a == 1) { // H: key k -> hg=k/80, kh=k%80; sum over 32 ds
            const int hg = k / 80, kh = k % 80;
            const float* p = bb + (size_t)hg * SLOT + 5 + kh;
            for (int ds = 0; ds < 32; ++ds) val += p[(size_t)(ds * 2) * SLOT];
        } else {             // W: key k; sum over all 64 (ds,hg)
            const float* p = bb + 85 + k;
            for (int i = 0; i < 64; ++i) val += p[(size_t)i * SLOT];
        }
        kv = expf(val * f);
    }
    for (int off = 32; off > 0; off >>= 1) kv += __shfl_down(kv, off, 64);
    if (threadIdx.x == 0) part[blockIdx.x] = kv;
}

__global__ __launch_bounds__(64) void final_kernel(const float* __restrict__ part,
                                                   float* __restrict__ out) {
    float v = (threadIdx.x < NFIN) ? part[threadIdx.x] : 0.f;
    for (int off = 32; off > 0; off >>= 1) v += __shfl_down(v, off, 64);
    if (threadIdx.x == 0) out[0] = -v / (float)NKEY;
}

extern "C" void kernel_launch(void* const* d_in, const int* in_sizes, int n_in,
                              void* d_out, int out_size, void* d_ws, size_t ws_size,
                              hipStream_t stream) {
    const float* x = (const float*)d_in[0];
    const float* log_sigma = (const float*)d_in[1];
    float* out = (float*)d_out;
    float* ws = (float*)d_ws;

    diff3_kernel<<<NBLK, 320, 0, stream>>>(x, ws);
    reduce_kernel<<<NFIN, 64, 0, stream>>>(ws, log_sigma, ws + PART_OFF);
    final_kernel<<<1, 64, 0, stream>>>(ws + PART_OFF, out);
}

// Round 10
// 198.363 us; speedup vs baseline: 1.3024x; 1.3024x over previous
//
#include <hip/hip_runtime.h>

// x: [8, 1, 160, 160, 160] fp32; log_sigma: [3] fp32; out: scalar fp32.
// loss = -(sum over 3816 (axis,b,pair) of exp(-sq/(2*sigma_axis^2))) / 3816.
//
// R10 = R6 VERBATIM (confirmed best: 195.9us). Every perturbation regressed:
// R7 global atomics +32us (cross-XCD cacheline ping-pong), R8 full reg hoist
// neutral, R9 10-row tile spilled (VGPR 128 cap at 320thr -> 110MB scratch
// WRITE). Thread owns 4 consecutive rows x 1 float4-col x 5 slices: 3/4
// h-pairs register-local; w-boundary via __shfl_down; d via rolling regs +
// 1 halo slice per 5. Private per-block ws slots; no atomics; no zero kernel.

constexpr int Wd4 = 40;              // float4 per row
constexpr int SLICE4 = 6400;         // float4 per slice
constexpr long BSTR4 = 160L * 6400;  // float4 per batch
constexpr int NB = 8;
constexpr int NPAIR = 159;
constexpr int NKEY = 3 * NB * NPAIR;   // 3816
constexpr int SLOT = 200;              // floats/slot: [0..4]=D [5..36]=H [37..196]=W
constexpr int NBLK = NB * 160;         // 8 b x 32 ds x 5 hc = 1280
constexpr int PART_OFF = NBLK * SLOT;  // float offset of reduce partials in ws
constexpr int NFIN = 60;

__device__ __forceinline__ float sq4(const float4& a, const float4& c) {
    float e0 = a.x - c.x, e1 = a.y - c.y, e2 = a.z - c.z, e3 = a.w - c.w;
    return e0 * e0 + e1 * e1 + e2 * e2 + e3 * e3;
}

// 1280 blocks x 320 threads. bid -> (b, ds 0..31, hc 0..4). Thread: c4=t%40,
// rp=t/40 owns rows h0+4rp+{0..3}. Slices d0..d0+4 owned, d0+5 halo (v only).
__global__ __launch_bounds__(320) void diff3_kernel(const float* __restrict__ x,
                                                    float* __restrict__ ws) {
    __shared__ float lds[1504];  // H: [0..1311] 32 keys*41; D: [1472..1496]; W reuses [0..1439]

    const int t = threadIdx.x;
    const int bid = blockIdx.x;
    const int b = bid / 160;
    const int r2 = bid % 160;
    const int ds = r2 / 5;     // d-segment, d0 = 5*ds
    const int hc = r2 % 5;     // h-chunk,  h0 = 32*hc
    const int d0 = ds * 5, h0 = hc * 32;
    const bool lastSeg = (ds == 31);

    const int c4 = t % 40;
    const int rp = t / 40;                  // 0..7
    const int lane = t & 63;
    const int wv = t >> 6;                  // wave 0..4
    const bool hOK = !(hc == 4 && rp == 7); // row h0+4rp+4 <= 159
    const bool sOK = (c4 < 39);
    const bool fixB = (lane == 63) && sOK;  // shfl partner in next wave -> load

    const float4* base = (const float4*)x + (size_t)b * BSTR4 + (size_t)d0 * SLICE4
                       + (size_t)(h0 + 4 * rp) * Wd4 + c4;

    float aW[4] = {0.f, 0.f, 0.f, 0.f};
    float aH[4] = {0.f, 0.f, 0.f, 0.f};
    float aD[5] = {0.f, 0.f, 0.f, 0.f, 0.f};
    float4 p0, p1, p2, p3;

#pragma unroll
    for (int it = 0; it < 5; ++it) {
        const float4* sp = base + it * SLICE4;
        const float4 v0 = sp[0];
        const float4 v1 = sp[Wd4];
        const float4 v2 = sp[2 * Wd4];
        const float4 v3 = sp[3 * Wd4];
        float4 hv;
        if (hOK) hv = sp[4 * Wd4];
        float bx0 = 0.f, bx1 = 0.f, bx2 = 0.f, bx3 = 0.f;
        if (fixB) {  // cross-wave w-boundary partner: scalar loads (4 thr/block)
            bx0 = ((const float*)(sp))[4];
            bx1 = ((const float*)(sp + Wd4))[4];
            bx2 = ((const float*)(sp + 2 * Wd4))[4];
            bx3 = ((const float*)(sp + 3 * Wd4))[4];
        }
        // w-boundary partner .x from lane+1 (same row, next float4)
        float s0 = __shfl_down(v0.x, 1, 64); if (fixB) s0 = bx0;
        float s1 = __shfl_down(v1.x, 1, 64); if (fixB) s1 = bx1;
        float s2 = __shfl_down(v2.x, 1, 64); if (fixB) s2 = bx2;
        float s3 = __shfl_down(v3.x, 1, 64); if (fixB) s3 = bx3;

        float dw;
        dw = v0.y - v0.x; aW[0] += dw * dw;
        dw = v0.z - v0.y; aW[1] += dw * dw;
        dw = v0.w - v0.z; aW[2] += dw * dw;
        dw = v1.y - v1.x; aW[0] += dw * dw;
        dw = v1.z - v1.y; aW[1] += dw * dw;
        dw = v1.w - v1.z; aW[2] += dw * dw;
        dw = v2.y - v2.x; aW[0] += dw * dw;
        dw = v2.z - v2.y; aW[1] += dw * dw;
        dw = v2.w - v2.z; aW[2] += dw * dw;
        dw = v3.y - v3.x; aW[0] += dw * dw;
        dw = v3.z - v3.y; aW[1] += dw * dw;
        dw = v3.w - v3.z; aW[2] += dw * dw;
        if (sOK) {
            dw = s0 - v0.w; aW[3] += dw * dw;
            dw = s1 - v1.w; aW[3] += dw * dw;
            dw = s2 - v2.w; aW[3] += dw * dw;
            dw = s3 - v3.w; aW[3] += dw * dw;
        }
        // h: 3 register-local pairs + 1 via hv
        aH[0] += sq4(v1, v0);
        aH[1] += sq4(v2, v1);
        aH[2] += sq4(v3, v2);
        if (hOK) aH[3] += sq4(hv, v3);
        // d: vs previous slice (rolling regs)
        if (it > 0)
            aD[it - 1] += sq4(v0, p0) + sq4(v1, p1) + sq4(v2, p2) + sq4(v3, p3);
        p0 = v0; p1 = v1; p2 = v2; p3 = v3;  // SSA under full unroll
    }
    if (!lastSeg) {  // halo slice d0+5: v-only, completes pair key d0+4
        const float4* sp = base + 5 * SLICE4;
        aD[4] = sq4(sp[0], p0) + sq4(sp[Wd4], p1) + sq4(sp[2 * Wd4], p2) + sq4(sp[3 * Wd4], p3);
    }

    // ---- flush. Phase 1: H per-key scratch + D wave-reduce.
#pragma unroll
    for (int j = 0; j < 4; ++j) lds[(4 * rp + j) * 41 + c4] = aH[j];
#pragma unroll
    for (int j = 0; j < 5; ++j) {
        float dd = aD[j];
        for (int off = 32; off > 0; off >>= 1) dd += __shfl_down(dd, off, 64);
        if (lane == 0) lds[1472 + j * 5 + wv] = dd;
    }
    __syncthreads();
    float hsum = 0.f, dsum = 0.f;
    if (t < 32) {
        const float* src = &lds[t * 41];
        for (int i = 0; i < 40; ++i) hsum += src[i];
    }
    if (t < 5) {
        for (int w2 = 0; w2 < 5; ++w2) dsum += lds[1472 + t * 5 + w2];
    }
    __syncthreads();  // H region reads done; reuse for W
    // Phase 2: W per-key scratch (key 4c4+j, 8 contributors rp).
#pragma unroll
    for (int j = 0; j < 4; ++j) lds[(4 * c4 + j) * 9 + rp] = aW[j];
    __syncthreads();
    float wsum = 0.f;
    if (t < 160) {
        const float* src = &lds[t * 9];
        for (int i = 0; i < 8; ++i) wsum += src[i];
    }
    // Private slot write (no atomics; every used slot float written).
    float* slot = ws + (size_t)bid * SLOT;
    if (t < 5)   slot[t] = dsum;
    if (t < 32)  slot[5 + t] = hsum;
    if (t < 160) slot[37 + t] = wsum;
}

// 60 blocks x 64 threads: one thread per (axis,b,pair); sums contributing slots.
__global__ __launch_bounds__(64) void reduce_kernel(const float* __restrict__ ws,
                                                    const float* __restrict__ log_sigma,
                                                    float* __restrict__ part) {
    const int gk = blockIdx.x * 64 + threadIdx.x;
    float kv = 0.f;
    if (gk < NKEY) {
        const int a = gk / (NB * NPAIR);
        const int rem = gk % (NB * NPAIR);
        const int b = rem / NPAIR;
        const int k = rem % NPAIR;
        const float f = -0.5f * expf(-2.f * log_sigma[a]);  // -1/(2*sigma^2)
        const float* bb = ws + (size_t)b * 160 * SLOT;
        float val = 0.f;
        if (a == 0) {        // D: key k -> ds=k/5, j=k%5, sum over 5 hc
            const int ds = k / 5, j = k % 5;
            const float* p = bb + (size_t)(ds * 5) * SLOT + j;
            for (int hc = 0; hc < 5; ++hc) val += p[hc * SLOT];
        } else if (a == 1) { // H: key k -> hc=k/32, kk=k%32, sum over 32 ds
            const int hc = k / 32, kk = k % 32;
            const float* p = bb + (size_t)hc * SLOT + 5 + kk;
            for (int ds = 0; ds < 32; ++ds) val += p[(size_t)(ds * 5) * SLOT];
        } else {             // W: key k, sum over all 160 (ds,hc)
            const float* p = bb + 37 + k;
            for (int i = 0; i < 160; ++i) val += p[(size_t)i * SLOT];
        }
        kv = expf(val * f);
    }
    for (int off = 32; off > 0; off >>= 1) kv += __shfl_down(kv, off, 64);
    if (threadIdx.x == 0) part[blockIdx.x] = kv;
}

__global__ __launch_bounds__(64) void final_kernel(const float* __restrict__ part,
                                                   float* __restrict__ out) {
    float v = (threadIdx.x < NFIN) ? part[threadIdx.x] : 0.f;
    for (int off = 32; off > 0; off >>= 1) v += __shfl_down(v, off, 64);
    if (threadIdx.x == 0) out[0] = -v / (float)NKEY;
}

extern "C" void kernel_launch(void* const* d_in, const int* in_sizes, int n_in,
                              void* d_out, int out_size, void* d_ws, size_t ws_size,
                              hipStream_t stream) {
    const float* x = (const float*)d_in[0];
    const float* log_sigma = (const float*)d_in[1];
    float* out = (float*)d_out;
    float* ws = (float*)d_ws;

    diff3_kernel<<<NBLK, 320, 0, stream>>>(x, ws);
    reduce_kernel<<<NFIN, 64, 0, stream>>>(ws, log_sigma, ws + PART_OFF);
    final_kernel<<<1, 64, 0, stream>>>(ws + PART_OFF, out);
}